// Round 4
// baseline (712.552 us; speedup 1.0000x reference)
//
#include <hip/hip_runtime.h>

typedef __bf16 bf16x8 __attribute__((ext_vector_type(8)));
typedef float  f32x4  __attribute__((ext_vector_type(4)));
typedef unsigned short us8 __attribute__((ext_vector_type(8)));
typedef unsigned short us4 __attribute__((ext_vector_type(4)));

__device__ __forceinline__ float bf2f(unsigned short u) {
    return __builtin_bit_cast(float, (unsigned int)u << 16);
}
__device__ __forceinline__ unsigned short f2bf(float f) {
    return __builtin_bit_cast(unsigned short, (__bf16)f);
}

#define MEGA_NB 448

// Software grid barrier (co-resident grid only). Monotonic counter, zeroed by
// memset before launch. Agent-scope fences force L2 wb/inv on every XCD
// (every block fences), making plain cross-stage loads/stores safe.
__device__ __forceinline__ void gridbar(int* bar, int k) {
    __syncthreads();
    if (threadIdx.x == 0) {
        __threadfence();   // release: waits vmcnt, L2 writeback (agent scope)
        __hip_atomic_fetch_add(bar, 1, __ATOMIC_RELAXED, __HIP_MEMORY_SCOPE_AGENT);
        while (__hip_atomic_load(bar, __ATOMIC_RELAXED, __HIP_MEMORY_SCOPE_AGENT) < MEGA_NB * k)
            __builtin_amdgcn_s_sleep(2);
        __threadfence();   // acquire: L2/L1 invalidate
    }
    __syncthreads();
}

// ---------------- fused CSR build + weight prep (single dispatch, 4 grid barriers) ----------------
// stage0: weight split/transpose + degree count (atomics)
// stage1: per-256-chunk exclusive scan, chunk totals -> csum
// stage2: block 0 scans csum (exclusive)
// stage3: absolute rowptr, cursor init, dinv/selfw
// stage4: fill edge records epack = {src, dinv[src]*dinv[dst]}
__global__ __launch_bounds__(256, 2) void csr_mega(
    const float* __restrict__ W0, const float* __restrict__ W1f,
    const float* __restrict__ W2f, const float* __restrict__ W3f,
    unsigned short* __restrict__ wt,
    const int* __restrict__ src, const int* __restrict__ dst,
    int* __restrict__ cnt, int* __restrict__ rowptr, int* __restrict__ csum,
    float* __restrict__ dinv, float* __restrict__ selfw, int* __restrict__ cursor,
    int2* __restrict__ epack, int* __restrict__ bar, int N, int E)
{
    const int tid = threadIdx.x;
    const int gtid = blockIdx.x * 256 + tid;
    const int GT = MEGA_NB * 256;
    __shared__ int s[256];
    __shared__ int carry_s;

    // ---- stage 0: weights + degree count ----
    if (gtid < 65536) {
        int m = gtid >> 14, r = gtid & 16383;
        const float* W = (m == 0) ? W0 : (m == 1) ? W1f : (m == 2) ? W2f : W3f;
        float f = W[r];
        int k = r >> 7, n = r & 127;
        __bf16 h = (__bf16)f;
        __bf16 l = (__bf16)(f - (float)h);
        unsigned short* base = wt + m * 32768;
        base[n * 128 + k]         = __builtin_bit_cast(unsigned short, h);
        base[16384 + n * 128 + k] = __builtin_bit_cast(unsigned short, l);
    }
    for (int e = gtid; e < E; e += GT) atomicAdd(&cnt[dst[e]], 1);
    gridbar(bar, 1);

    // ---- stage 1: chunk scans ----
    const int nchunks = (N + 255) >> 8;
    for (int c = blockIdx.x; c < nchunks; c += MEGA_NB) {
        int idx = c * 256 + tid;
        int v = (idx < N) ? cnt[idx] : 0;
        int sum = v;
        s[tid] = sum;
        __syncthreads();
        for (int o = 1; o < 256; o <<= 1) {
            int u = (tid >= o) ? s[tid - o] : 0;
            __syncthreads();
            sum += u;
            s[tid] = sum;
            __syncthreads();
        }
        if (idx < N) rowptr[idx] = sum - v;     // chunk-local exclusive
        if (tid == 255) csum[c] = sum;          // chunk total
        __syncthreads();
    }
    gridbar(bar, 2);

    // ---- stage 2: scan chunk totals (block 0) ----
    if (blockIdx.x == 0) {
        if (tid == 0) carry_s = 0;
        __syncthreads();
        for (int base = 0; base < nchunks; base += 256) {
            int idx = base + tid;
            int v = (idx < nchunks) ? csum[idx] : 0;
            int sum = v;
            s[tid] = sum;
            __syncthreads();
            for (int o = 1; o < 256; o <<= 1) {
                int u = (tid >= o) ? s[tid - o] : 0;
                __syncthreads();
                sum += u;
                s[tid] = sum;
                __syncthreads();
            }
            int c0 = carry_s;
            if (idx < nchunks) csum[idx] = c0 + sum - v;   // exclusive
            __syncthreads();
            if (tid == 255) carry_s = c0 + sum;
            __syncthreads();
        }
    }
    gridbar(bar, 3);

    // ---- stage 3: finalize ----
    for (int i = gtid; i < N; i += GT) {
        int a = rowptr[i] + csum[i >> 8];
        rowptr[i] = a;
        cursor[i] = a;
        float dv = rsqrtf((float)(cnt[i] + 1));
        dinv[i] = dv;
        selfw[i] = dv * dv;
    }
    if (gtid == 0) rowptr[N] = E;
    gridbar(bar, 4);

    // ---- stage 4: fill edge records ----
    for (int e = gtid; e < E; e += GT) {
        int sv = src[e], d = dst[e];
        float w = dinv[sv] * dinv[d];
        int p = atomicAdd(&cursor[d], 1);
        int2 rec;
        rec.x = sv;
        rec.y = __builtin_bit_cast(int, w);
        epack[p] = rec;
    }
}

// ---------------- GEMM: C[M,128] = A[M,128] @ W[128,128](split hi/lo bf16) ----------------
// aF32: A is f32 (converted in-flight) else bf16 plane.
// mode 0: no bias -> Cb bf16; mode 2: +bias -> Cf f32
__global__ __launch_bounds__(256) void gemm128s(
    const void* __restrict__ A, int aF32,
    const unsigned short* __restrict__ WhiT, const unsigned short* __restrict__ WloT,
    const float* __restrict__ bias, float* __restrict__ Cf,
    unsigned short* __restrict__ Cb, int M, int mode)
{
    __shared__ unsigned short sHi[128 * 136];
    __shared__ unsigned short sLo[128 * 136];
    const int tid = threadIdx.x;

    for (int i = tid; i < 2048; i += 256) {
        int row = i >> 4, seg = i & 15;
        *(us8*)(&sHi[row * 136 + seg * 8]) = *(const us8*)(WhiT + row * 128 + seg * 8);
        *(us8*)(&sLo[row * 136 + seg * 8]) = *(const us8*)(WloT + row * 128 + seg * 8);
    }
    __syncthreads();

    const int lane = tid & 63;
    const int wave = tid >> 6;
    const int lc   = lane & 15;
    const int quad = lane >> 4;
    const int rowBlock = blockIdx.x * 128 + wave * 32;

    f32x4 acc[2][8];
    const f32x4 z4 = {0.f, 0.f, 0.f, 0.f};
#pragma unroll
    for (int rs = 0; rs < 2; ++rs)
#pragma unroll
        for (int t = 0; t < 8; ++t) acc[rs][t] = z4;

#pragma unroll
    for (int ks = 0; ks < 4; ++ks) {
        const int kf = ks * 32 + quad * 8;
        bf16x8 a[2];
#pragma unroll
        for (int rs = 0; rs < 2; ++rs) {
            int r = rowBlock + rs * 16 + lc;
            if (r > M - 1) r = M - 1;
            if (aF32) {
                const f32x4* ap = (const f32x4*)((const float*)A + (size_t)r * 128 + kf);
                f32x4 a0 = ap[0], a1 = ap[1];
                bf16x8 av;
#pragma unroll
                for (int j = 0; j < 4; ++j) av[j] = (__bf16)a0[j];
#pragma unroll
                for (int j = 0; j < 4; ++j) av[4 + j] = (__bf16)a1[j];
                a[rs] = av;
            } else {
                a[rs] = __builtin_bit_cast(bf16x8,
                        *(const us8*)((const unsigned short*)A + (size_t)r * 128 + kf));
            }
        }
#pragma unroll
        for (int t = 0; t < 8; ++t) {
            bf16x8 bhi = __builtin_bit_cast(bf16x8, *(const us8*)(&sHi[(t * 16 + lc) * 136 + kf]));
            bf16x8 blo = __builtin_bit_cast(bf16x8, *(const us8*)(&sLo[(t * 16 + lc) * 136 + kf]));
#pragma unroll
            for (int rs = 0; rs < 2; ++rs) {
                acc[rs][t] = __builtin_amdgcn_mfma_f32_16x16x32_bf16(a[rs], bhi, acc[rs][t], 0, 0, 0);
                acc[rs][t] = __builtin_amdgcn_mfma_f32_16x16x32_bf16(a[rs], blo, acc[rs][t], 0, 0, 0);
            }
        }
    }

#pragma unroll
    for (int t = 0; t < 8; ++t) {
        int gcol = t * 16 + lc;
        float bv = (mode != 0) ? bias[gcol] : 0.f;
#pragma unroll
        for (int rs = 0; rs < 2; ++rs) {
#pragma unroll
            for (int i = 0; i < 4; ++i) {
                int r = rowBlock + rs * 16 + quad * 4 + i;
                if (r < M) {
                    float v = acc[rs][t][i] + bv;
                    if (mode == 2) Cf[(size_t)r * 128 + gcol] = v;
                    else           Cb[(size_t)r * 128 + gcol] = f2bf(v);
                }
            }
        }
    }
}

// ---------------- fused projection: p = prelu(z@Wp1+bp1)@Wp2+bp2 (row-block local) ----------------
__global__ __launch_bounds__(256) void proj2(
    const unsigned short* __restrict__ Z, const unsigned short* __restrict__ wtp1,
    const unsigned short* __restrict__ wtp2, const float* __restrict__ bp1,
    const float* __restrict__ prelu_a, const float* __restrict__ bp2,
    unsigned short* __restrict__ T1, float* __restrict__ P, int M)
{
    __shared__ unsigned short sHi[128 * 136];
    __shared__ unsigned short sLo[128 * 136];
    const int tid = threadIdx.x;
    const int lane = tid & 63;
    const int wave = tid >> 6;
    const int lc   = lane & 15;
    const int quad = lane >> 4;
    const int rowBlock = blockIdx.x * 128 + wave * 32;
    const f32x4 z4 = {0.f, 0.f, 0.f, 0.f};

    // ---- pass 1: T1 = prelu(Z @ Wp1 + bp1) ----
    for (int i = tid; i < 2048; i += 256) {
        int row = i >> 4, seg = i & 15;
        *(us8*)(&sHi[row * 136 + seg * 8]) = *(const us8*)(wtp1 + row * 128 + seg * 8);
        *(us8*)(&sLo[row * 136 + seg * 8]) = *(const us8*)(wtp1 + 16384 + row * 128 + seg * 8);
    }
    __syncthreads();

    f32x4 acc[2][8];
#pragma unroll
    for (int rs = 0; rs < 2; ++rs)
#pragma unroll
        for (int t = 0; t < 8; ++t) acc[rs][t] = z4;

#pragma unroll
    for (int ks = 0; ks < 4; ++ks) {
        const int kf = ks * 32 + quad * 8;
        bf16x8 a[2];
#pragma unroll
        for (int rs = 0; rs < 2; ++rs) {
            int r = rowBlock + rs * 16 + lc;
            if (r > M - 1) r = M - 1;
            a[rs] = __builtin_bit_cast(bf16x8, *(const us8*)(Z + (size_t)r * 128 + kf));
        }
#pragma unroll
        for (int t = 0; t < 8; ++t) {
            bf16x8 bhi = __builtin_bit_cast(bf16x8, *(const us8*)(&sHi[(t * 16 + lc) * 136 + kf]));
            bf16x8 blo = __builtin_bit_cast(bf16x8, *(const us8*)(&sLo[(t * 16 + lc) * 136 + kf]));
#pragma unroll
            for (int rs = 0; rs < 2; ++rs) {
                acc[rs][t] = __builtin_amdgcn_mfma_f32_16x16x32_bf16(a[rs], bhi, acc[rs][t], 0, 0, 0);
                acc[rs][t] = __builtin_amdgcn_mfma_f32_16x16x32_bf16(a[rs], blo, acc[rs][t], 0, 0, 0);
            }
        }
    }

    float av = prelu_a[0];
#pragma unroll
    for (int t = 0; t < 8; ++t) {
        int gcol = t * 16 + lc;
        float bv = bp1[gcol];
#pragma unroll
        for (int rs = 0; rs < 2; ++rs) {
#pragma unroll
            for (int i = 0; i < 4; ++i) {
                int r = rowBlock + rs * 16 + quad * 4 + i;
                if (r < M) {
                    float v = acc[rs][t][i] + bv;
                    v = (v > 0.f) ? v : av * v;
                    T1[(size_t)r * 128 + gcol] = f2bf(v);
                }
            }
        }
    }

    __threadfence();     // drain T1 stores (vmcnt) + L1 inv before re-reading
    __syncthreads();

    // ---- pass 2: P = T1 @ Wp2 + bp2 ----
    for (int i = tid; i < 2048; i += 256) {
        int row = i >> 4, seg = i & 15;
        *(us8*)(&sHi[row * 136 + seg * 8]) = *(const us8*)(wtp2 + row * 128 + seg * 8);
        *(us8*)(&sLo[row * 136 + seg * 8]) = *(const us8*)(wtp2 + 16384 + row * 128 + seg * 8);
    }
    __syncthreads();

#pragma unroll
    for (int rs = 0; rs < 2; ++rs)
#pragma unroll
        for (int t = 0; t < 8; ++t) acc[rs][t] = z4;

#pragma unroll
    for (int ks = 0; ks < 4; ++ks) {
        const int kf = ks * 32 + quad * 8;
        bf16x8 a[2];
#pragma unroll
        for (int rs = 0; rs < 2; ++rs) {
            int r = rowBlock + rs * 16 + lc;
            if (r > M - 1) r = M - 1;
            a[rs] = __builtin_bit_cast(bf16x8, *(const us8*)(T1 + (size_t)r * 128 + kf));
        }
#pragma unroll
        for (int t = 0; t < 8; ++t) {
            bf16x8 bhi = __builtin_bit_cast(bf16x8, *(const us8*)(&sHi[(t * 16 + lc) * 136 + kf]));
            bf16x8 blo = __builtin_bit_cast(bf16x8, *(const us8*)(&sLo[(t * 16 + lc) * 136 + kf]));
#pragma unroll
            for (int rs = 0; rs < 2; ++rs) {
                acc[rs][t] = __builtin_amdgcn_mfma_f32_16x16x32_bf16(a[rs], bhi, acc[rs][t], 0, 0, 0);
                acc[rs][t] = __builtin_amdgcn_mfma_f32_16x16x32_bf16(a[rs], blo, acc[rs][t], 0, 0, 0);
            }
        }
    }

#pragma unroll
    for (int t = 0; t < 8; ++t) {
        int gcol = t * 16 + lc;
        float bv = bp2[gcol];
#pragma unroll
        for (int rs = 0; rs < 2; ++rs) {
#pragma unroll
            for (int i = 0; i < 4; ++i) {
                int r = rowBlock + rs * 16 + quad * 4 + i;
                if (r < M) P[(size_t)r * 128 + gcol] = acc[rs][t][i] + bv;
            }
        }
    }
}

// ---------------- GCN aggregation: 32-lane group per node, 8-deep gather unroll ----------------
__global__ __launch_bounds__(256) void aggregate(
    const unsigned short* __restrict__ Hhi, const float* __restrict__ selfw,
    const int* __restrict__ rowptr, const int2* __restrict__ epack,
    const float* __restrict__ bias, float* __restrict__ outF,
    unsigned short* __restrict__ outHi, int N)
{
    const int tid = threadIdx.x;
    const int g = tid >> 5;
    const int l = tid & 31;
    const int n = blockIdx.x * 8 + g;
    if (n >= N) return;

    const int beg = rowptr[n], end = rowptr[n + 1];
    const size_t fo = (size_t)l * 4;

    f32x4 acc[4];
    const f32x4 z4 = {0.f, 0.f, 0.f, 0.f};
#pragma unroll
    for (int u = 0; u < 4; ++u) acc[u] = z4;

    int i = beg;
    for (; i + 7 < end; i += 8) {
        int2 e[8];
        us4 h[8];
#pragma unroll
        for (int u = 0; u < 8; ++u) e[u] = epack[i + u];
#pragma unroll
        for (int u = 0; u < 8; ++u) h[u] = *(const us4*)(Hhi + (size_t)e[u].x * 128 + fo);
#pragma unroll
        for (int u = 0; u < 8; ++u) {
            float w = __builtin_bit_cast(float, e[u].y);
#pragma unroll
            for (int j = 0; j < 4; ++j) acc[u & 3][j] += w * bf2f(h[u][j]);
        }
    }
    if (i + 3 < end) {
        int2 e[4];
        us4 h[4];
#pragma unroll
        for (int u = 0; u < 4; ++u) e[u] = epack[i + u];
#pragma unroll
        for (int u = 0; u < 4; ++u) h[u] = *(const us4*)(Hhi + (size_t)e[u].x * 128 + fo);
#pragma unroll
        for (int u = 0; u < 4; ++u) {
            float w = __builtin_bit_cast(float, e[u].y);
#pragma unroll
            for (int j = 0; j < 4; ++j) acc[u][j] += w * bf2f(h[u][j]);
        }
        i += 4;
    }
    for (; i < end; ++i) {
        int2 e0 = epack[i];
        us4 h0 = *(const us4*)(Hhi + (size_t)e0.x * 128 + fo);
        float w0 = __builtin_bit_cast(float, e0.y);
#pragma unroll
        for (int j = 0; j < 4; ++j) acc[0][j] += w0 * bf2f(h0[j]);
    }

    float sw = selfw[n];
    us4 sh = *(const us4*)(Hhi + (size_t)n * 128 + fo);
    f32x4 b4 = *(const f32x4*)(bias + l * 4);
    f32x4 sum = (acc[0] + acc[1]) + (acc[2] + acc[3]);
    f32x4 v;
    us4 ob;
#pragma unroll
    for (int j = 0; j < 4; ++j) {
        v[j] = fmaxf(sum[j] + sw * bf2f(sh[j]) + b4[j], 0.f);
        ob[j] = f2bf(v[j]);
    }
    if (outF) *(f32x4*)(outF + (size_t)n * 128 + fo) = v;
    *(us4*)(outHi + (size_t)n * 128 + fo) = ob;
}

// ---------------- launch ----------------
extern "C" void kernel_launch(void* const* d_in, const int* in_sizes, int n_in,
                              void* d_out, int out_size, void* d_ws, size_t ws_size,
                              hipStream_t stream)
{
    const float* x   = (const float*)d_in[0];
    const int*   ei  = (const int*)d_in[1];
    const float* W1  = (const float*)d_in[2];
    const float* b1  = (const float*)d_in[3];
    const float* W2  = (const float*)d_in[4];
    const float* b2  = (const float*)d_in[5];
    const float* Wp1 = (const float*)d_in[6];
    const float* bp1 = (const float*)d_in[7];
    const float* pa  = (const float*)d_in[8];
    const float* Wp2 = (const float*)d_in[9];
    const float* bp2 = (const float*)d_in[10];

    const int N = in_sizes[0] / 128;
    const int E = in_sizes[1] / 2;
    const int* src = ei;
    const int* dst = ei + E;

    float* outF = (float*)d_out;
    float* zbuf = outF;                        // output 0: z
    float* pbuf = outF + (size_t)N * 128;      // output 1: p

    char* w = (char*)d_ws;
    size_t off = 0;
    auto alloc = [&](size_t bytes) {
        void* p = w + off;
        off = (off + bytes + 255) & ~(size_t)255;
        return p;
    };
    unsigned short* S1 = (unsigned short*)alloc((size_t)N * 128 * sizeof(unsigned short));
    unsigned short* S2 = (unsigned short*)alloc((size_t)N * 128 * sizeof(unsigned short));
    float* dinv   = (float*)alloc((size_t)N * sizeof(float));
    float* selfw  = (float*)alloc((size_t)N * sizeof(float));
    int*   rowptr = (int*)alloc((size_t)(N + 1) * sizeof(int));
    int*   cnt    = (int*)alloc((size_t)(N + 8) * sizeof(int));   // + barrier ints
    int*   bar    = cnt + N;
    int*   cursor = (int*)alloc((size_t)N * sizeof(int));
    int*   csum   = (int*)alloc((size_t)1024 * sizeof(int));
    int2*  epack  = (int2*)alloc((size_t)E * sizeof(int2));
    unsigned short* wt = (unsigned short*)alloc((size_t)4 * 2 * 128 * 128 * sizeof(unsigned short));
    (void)ws_size; (void)n_in; (void)out_size;

    auto hiP = [&](int m) { return wt + (size_t)m * 32768; };
    auto loP = [&](int m) { return wt + (size_t)m * 32768 + 16384; };

    // zero degree counters + barrier
    hipMemsetAsync(cnt, 0, (size_t)(N + 8) * sizeof(int), stream);

    // fused weight prep + CSR build
    hipLaunchKernelGGL(csr_mega, dim3(MEGA_NB), dim3(256), 0, stream,
                       W1, W2, Wp1, Wp2, wt, src, dst, cnt, rowptr, csum,
                       dinv, selfw, cursor, epack, bar, N, E);

    const int gb = (N + 127) / 128;
    const int ab = (N + 7) / 8;
    // conv1: h1 = x@W1 (f32 A, converted in-flight) -> S2 ; z1 = relu(agg+b1) -> S1
    hipLaunchKernelGGL(gemm128s, dim3(gb), dim3(256), 0, stream, (const void*)x, 1,
                       hiP(0), loP(0), (const float*)nullptr, (float*)nullptr, S2, N, 0);
    hipLaunchKernelGGL(aggregate, dim3(ab), dim3(256), 0, stream, S2, selfw, rowptr, epack,
                       b1, (float*)nullptr, S1, N);
    // conv2: h2 = z1@W2 -> S2 ; z = relu(agg+b2) -> zbuf(f32) + S1(bf16)
    hipLaunchKernelGGL(gemm128s, dim3(gb), dim3(256), 0, stream, (const void*)S1, 0,
                       hiP(1), loP(1), (const float*)nullptr, (float*)nullptr, S2, N, 0);
    hipLaunchKernelGGL(aggregate, dim3(ab), dim3(256), 0, stream, S2, selfw, rowptr, epack,
                       b2, zbuf, S1, N);
    // fused projection: p = prelu(z@Wp1+bp1)@Wp2+bp2 -> pbuf (T1 round-trips via S2)
    hipLaunchKernelGGL(proj2, dim3(gb), dim3(256), 0, stream, S1, hiP(2), hiP(3),
                       bp1, pa, bp2, S2, pbuf, N);
}

// Round 5
// 515.733 us; speedup vs baseline: 1.3816x; 1.3816x over previous
//
#include <hip/hip_runtime.h>

typedef __bf16 bf16x8 __attribute__((ext_vector_type(8)));
typedef float  f32x4  __attribute__((ext_vector_type(4)));
typedef unsigned short us8 __attribute__((ext_vector_type(8)));
typedef unsigned short us4 __attribute__((ext_vector_type(4)));

__device__ __forceinline__ float bf2f(unsigned short u) {
    return __builtin_bit_cast(float, (unsigned int)u << 16);
}
__device__ __forceinline__ unsigned short f2bf(float f) {
    return __builtin_bit_cast(unsigned short, (__bf16)f);
}

// ---------------- fused: weight prep (blocks 0..255) + degree count (blocks 256..) ----------------
// wt layout per matrix m: hiT[128*128], loT[128*128]
__global__ void prep_count(const float* __restrict__ W0, const float* __restrict__ W1,
                           const float* __restrict__ W2, const float* __restrict__ W3,
                           unsigned short* __restrict__ wt,
                           const int* __restrict__ dst, int* __restrict__ cnt, int E) {
    if (blockIdx.x < 256) {
        int i = blockIdx.x * 256 + threadIdx.x;    // 0..65535
        int m = i >> 14, r = i & 16383;
        const float* W = (m == 0) ? W0 : (m == 1) ? W1 : (m == 2) ? W2 : W3;
        float f = W[r];
        int k = r >> 7, n = r & 127;
        __bf16 h = (__bf16)f;
        __bf16 l = (__bf16)(f - (float)h);
        unsigned short* base = wt + m * 32768;
        base[n * 128 + k]         = __builtin_bit_cast(unsigned short, h);
        base[16384 + n * 128 + k] = __builtin_bit_cast(unsigned short, l);
    } else {
        int e = (blockIdx.x - 256) * 256 + threadIdx.x;
        if (e < E) atomicAdd(&cnt[dst[e]], 1);
    }
}

// ---------------- scan of PADDED degrees: pad = (cnt+7)&~7 ----------------
__global__ void scanA(const int* __restrict__ cnt, int* __restrict__ rowptr,
                      int* __restrict__ bsum, int N) {
    __shared__ int s[1024];
    int t = threadIdx.x;
    int idx = blockIdx.x * 1024 + t;
    int v = (idx < N) ? ((cnt[idx] + 7) & ~7) : 0;
    int sum = v;
    s[t] = sum;
    __syncthreads();
    for (int o = 1; o < 1024; o <<= 1) {
        int u = (t >= o) ? s[t - o] : 0;
        __syncthreads();
        sum += u;
        s[t] = sum;
        __syncthreads();
    }
    if (idx < N) rowptr[idx] = sum - v;       // block-local exclusive (padded)
    if (t == 1023) bsum[blockIdx.x] = sum;
}

// exclusive scan of block sums; also writes rowptr[N] = total padded edge count
__global__ void scanB(int* __restrict__ bsum, int nb, int* __restrict__ rowptr, int N) {
    __shared__ int s[128];
    int t = threadIdx.x;
    int v = (t < nb) ? bsum[t] : 0;
    int sum = v;
    s[t] = sum;
    __syncthreads();
    for (int o = 1; o < 128; o <<= 1) {
        int u = (t >= o) ? s[t - o] : 0;
        __syncthreads();
        sum += u;
        s[t] = sum;
        __syncthreads();
    }
    if (t < nb) bsum[t] = sum - v;
    if (t == 127) rowptr[N] = s[127];          // total (inclusive of last)
}

// finalize: absolute (padded) rowptr, fill cursor, dinv, selfw
__global__ void scanC(int* __restrict__ rowptr, const int* __restrict__ bsum,
                      const int* __restrict__ cnt, int* __restrict__ cursor,
                      float* __restrict__ dinv, float* __restrict__ selfw, int N) {
    int i = blockIdx.x * 256 + threadIdx.x;
    if (i < N) {
        int a = rowptr[i] + bsum[i >> 10];
        rowptr[i] = a;
        cursor[i] = a;
        float dv = rsqrtf((float)(cnt[i] + 1));
        dinv[i] = dv;
        selfw[i] = dv * dv;
    }
}

// fill edge records {src, dinv[src]*dinv[dst]}; threads >= E write padding {0, 0}
__global__ void fill_csr(const int* __restrict__ src, const int* __restrict__ dst,
                         int* __restrict__ cursor, const float* __restrict__ dinv,
                         const int* __restrict__ rowptr, const int* __restrict__ cnt,
                         int2* __restrict__ epack, int N, int E) {
    int e = blockIdx.x * 256 + threadIdx.x;
    if (e < E) {
        int s = src[e];
        int d = dst[e];
        float w = dinv[s] * dinv[d];
        int p = atomicAdd(&cursor[d], 1);
        int2 rec;
        rec.x = s;
        rec.y = __builtin_bit_cast(int, w);
        epack[p] = rec;
    } else if (e - E < N) {
        int i = e - E;
        int lo = rowptr[i] + cnt[i];
        int hi = rowptr[i + 1];
        int2 z; z.x = 0; z.y = 0;
        for (int j = lo; j < hi; ++j) epack[j] = z;
    }
}

// ---------------- GEMM: C[M,128] = A[M,128] @ W[128,128](split hi/lo bf16) ----------------
// aF32: A is f32 (converted in-flight) else bf16 plane. mode 0: -> Cb bf16
__global__ __launch_bounds__(256) void gemm128s(
    const void* __restrict__ A, int aF32,
    const unsigned short* __restrict__ WhiT, const unsigned short* __restrict__ WloT,
    unsigned short* __restrict__ Cb, int M)
{
    __shared__ unsigned short sHi[128 * 136];
    __shared__ unsigned short sLo[128 * 136];
    const int tid = threadIdx.x;

    for (int i = tid; i < 2048; i += 256) {
        int row = i >> 4, seg = i & 15;
        *(us8*)(&sHi[row * 136 + seg * 8]) = *(const us8*)(WhiT + row * 128 + seg * 8);
        *(us8*)(&sLo[row * 136 + seg * 8]) = *(const us8*)(WloT + row * 128 + seg * 8);
    }
    __syncthreads();

    const int lane = tid & 63;
    const int wave = tid >> 6;
    const int lc   = lane & 15;
    const int quad = lane >> 4;
    const int rowBlock = blockIdx.x * 128 + wave * 32;

    f32x4 acc[2][8];
    const f32x4 z4 = {0.f, 0.f, 0.f, 0.f};
#pragma unroll
    for (int rs = 0; rs < 2; ++rs)
#pragma unroll
        for (int t = 0; t < 8; ++t) acc[rs][t] = z4;

#pragma unroll
    for (int ks = 0; ks < 4; ++ks) {
        const int kf = ks * 32 + quad * 8;
        bf16x8 a[2];
#pragma unroll
        for (int rs = 0; rs < 2; ++rs) {
            int r = rowBlock + rs * 16 + lc;
            if (r > M - 1) r = M - 1;
            if (aF32) {
                const f32x4* ap = (const f32x4*)((const float*)A + (size_t)r * 128 + kf);
                f32x4 a0 = ap[0], a1 = ap[1];
                bf16x8 av;
#pragma unroll
                for (int j = 0; j < 4; ++j) av[j] = (__bf16)a0[j];
#pragma unroll
                for (int j = 0; j < 4; ++j) av[4 + j] = (__bf16)a1[j];
                a[rs] = av;
            } else {
                a[rs] = __builtin_bit_cast(bf16x8,
                        *(const us8*)((const unsigned short*)A + (size_t)r * 128 + kf));
            }
        }
#pragma unroll
        for (int t = 0; t < 8; ++t) {
            bf16x8 bhi = __builtin_bit_cast(bf16x8, *(const us8*)(&sHi[(t * 16 + lc) * 136 + kf]));
            bf16x8 blo = __builtin_bit_cast(bf16x8, *(const us8*)(&sLo[(t * 16 + lc) * 136 + kf]));
#pragma unroll
            for (int rs = 0; rs < 2; ++rs) {
                acc[rs][t] = __builtin_amdgcn_mfma_f32_16x16x32_bf16(a[rs], bhi, acc[rs][t], 0, 0, 0);
                acc[rs][t] = __builtin_amdgcn_mfma_f32_16x16x32_bf16(a[rs], blo, acc[rs][t], 0, 0, 0);
            }
        }
    }

#pragma unroll
    for (int t = 0; t < 8; ++t) {
        int gcol = t * 16 + lc;
#pragma unroll
        for (int rs = 0; rs < 2; ++rs) {
#pragma unroll
            for (int i = 0; i < 4; ++i) {
                int r = rowBlock + rs * 16 + quad * 4 + i;
                if (r < M) Cb[(size_t)r * 128 + gcol] = f2bf(acc[rs][t][i]);
            }
        }
    }
}

// ---------------- fused projection: p = prelu(z@Wp1+bp1)@Wp2+bp2 (row-block local) ----------------
__global__ __launch_bounds__(256) void proj2(
    const unsigned short* __restrict__ Z, const unsigned short* __restrict__ wtp1,
    const unsigned short* __restrict__ wtp2, const float* __restrict__ bp1,
    const float* __restrict__ prelu_a, const float* __restrict__ bp2,
    unsigned short* __restrict__ T1, float* __restrict__ P, int M)
{
    __shared__ unsigned short sHi[128 * 136];
    __shared__ unsigned short sLo[128 * 136];
    const int tid = threadIdx.x;
    const int lane = tid & 63;
    const int wave = tid >> 6;
    const int lc   = lane & 15;
    const int quad = lane >> 4;
    const int rowBlock = blockIdx.x * 128 + wave * 32;
    const f32x4 z4 = {0.f, 0.f, 0.f, 0.f};

    // ---- pass 1: T1 = prelu(Z @ Wp1 + bp1) ----
    for (int i = tid; i < 2048; i += 256) {
        int row = i >> 4, seg = i & 15;
        *(us8*)(&sHi[row * 136 + seg * 8]) = *(const us8*)(wtp1 + row * 128 + seg * 8);
        *(us8*)(&sLo[row * 136 + seg * 8]) = *(const us8*)(wtp1 + 16384 + row * 128 + seg * 8);
    }
    __syncthreads();

    f32x4 acc[2][8];
#pragma unroll
    for (int rs = 0; rs < 2; ++rs)
#pragma unroll
        for (int t = 0; t < 8; ++t) acc[rs][t] = z4;

#pragma unroll
    for (int ks = 0; ks < 4; ++ks) {
        const int kf = ks * 32 + quad * 8;
        bf16x8 a[2];
#pragma unroll
        for (int rs = 0; rs < 2; ++rs) {
            int r = rowBlock + rs * 16 + lc;
            if (r > M - 1) r = M - 1;
            a[rs] = __builtin_bit_cast(bf16x8, *(const us8*)(Z + (size_t)r * 128 + kf));
        }
#pragma unroll
        for (int t = 0; t < 8; ++t) {
            bf16x8 bhi = __builtin_bit_cast(bf16x8, *(const us8*)(&sHi[(t * 16 + lc) * 136 + kf]));
            bf16x8 blo = __builtin_bit_cast(bf16x8, *(const us8*)(&sLo[(t * 16 + lc) * 136 + kf]));
#pragma unroll
            for (int rs = 0; rs < 2; ++rs) {
                acc[rs][t] = __builtin_amdgcn_mfma_f32_16x16x32_bf16(a[rs], bhi, acc[rs][t], 0, 0, 0);
                acc[rs][t] = __builtin_amdgcn_mfma_f32_16x16x32_bf16(a[rs], blo, acc[rs][t], 0, 0, 0);
            }
        }
    }

    float av = prelu_a[0];
#pragma unroll
    for (int t = 0; t < 8; ++t) {
        int gcol = t * 16 + lc;
        float bv = bp1[gcol];
#pragma unroll
        for (int rs = 0; rs < 2; ++rs) {
#pragma unroll
            for (int i = 0; i < 4; ++i) {
                int r = rowBlock + rs * 16 + quad * 4 + i;
                if (r < M) {
                    float v = acc[rs][t][i] + bv;
                    v = (v > 0.f) ? v : av * v;
                    T1[(size_t)r * 128 + gcol] = f2bf(v);
                }
            }
        }
    }

    __threadfence();
    __syncthreads();

    // ---- pass 2: P = T1 @ Wp2 + bp2 ----
    for (int i = tid; i < 2048; i += 256) {
        int row = i >> 4, seg = i & 15;
        *(us8*)(&sHi[row * 136 + seg * 8]) = *(const us8*)(wtp2 + row * 128 + seg * 8);
        *(us8*)(&sLo[row * 136 + seg * 8]) = *(const us8*)(wtp2 + 16384 + row * 128 + seg * 8);
    }
    __syncthreads();

#pragma unroll
    for (int rs = 0; rs < 2; ++rs)
#pragma unroll
        for (int t = 0; t < 8; ++t) acc[rs][t] = z4;

#pragma unroll
    for (int ks = 0; ks < 4; ++ks) {
        const int kf = ks * 32 + quad * 8;
        bf16x8 a[2];
#pragma unroll
        for (int rs = 0; rs < 2; ++rs) {
            int r = rowBlock + rs * 16 + lc;
            if (r > M - 1) r = M - 1;
            a[rs] = __builtin_bit_cast(bf16x8, *(const us8*)(T1 + (size_t)r * 128 + kf));
        }
#pragma unroll
        for (int t = 0; t < 8; ++t) {
            bf16x8 bhi = __builtin_bit_cast(bf16x8, *(const us8*)(&sHi[(t * 16 + lc) * 136 + kf]));
            bf16x8 blo = __builtin_bit_cast(bf16x8, *(const us8*)(&sLo[(t * 16 + lc) * 136 + kf]));
#pragma unroll
            for (int rs = 0; rs < 2; ++rs) {
                acc[rs][t] = __builtin_amdgcn_mfma_f32_16x16x32_bf16(a[rs], bhi, acc[rs][t], 0, 0, 0);
                acc[rs][t] = __builtin_amdgcn_mfma_f32_16x16x32_bf16(a[rs], blo, acc[rs][t], 0, 0, 0);
            }
        }
    }

#pragma unroll
    for (int t = 0; t < 8; ++t) {
        int gcol = t * 16 + lc;
        float bv = bp2[gcol];
#pragma unroll
        for (int rs = 0; rs < 2; ++rs) {
#pragma unroll
            for (int i = 0; i < 4; ++i) {
                int r = rowBlock + rs * 16 + quad * 4 + i;
                if (r < M) P[(size_t)r * 128 + gcol] = acc[rs][t][i] + bv;
            }
        }
    }
}

// ---------------- GCN aggregation: 32-lane group per node, padded-to-8 edge lists ----------------
// Exact 8-deep unrolled loop, no tails (edge lists padded with {0, w=0} records).
__global__ __launch_bounds__(256) void aggregate(
    const unsigned short* __restrict__ Hhi, const float* __restrict__ selfw,
    const int* __restrict__ rowptr, const int2* __restrict__ epack,
    const float* __restrict__ bias, float* __restrict__ outF,
    unsigned short* __restrict__ outHi, int N)
{
    const int tid = threadIdx.x;
    const int g = tid >> 5;
    const int l = tid & 31;
    const int n = blockIdx.x * 8 + g;
    if (n >= N) return;

    const int beg = rowptr[n], end = rowptr[n + 1];   // end-beg is a multiple of 8
    const size_t fo = (size_t)l * 4;

    f32x4 acc[4];
    const f32x4 z4 = {0.f, 0.f, 0.f, 0.f};
#pragma unroll
    for (int u = 0; u < 4; ++u) acc[u] = z4;

    for (int i = beg; i < end; i += 8) {
        int2 e[8];
        us4 h[8];
#pragma unroll
        for (int u = 0; u < 8; ++u) e[u] = epack[i + u];
#pragma unroll
        for (int u = 0; u < 8; ++u) h[u] = *(const us4*)(Hhi + (size_t)e[u].x * 128 + fo);
#pragma unroll
        for (int u = 0; u < 8; ++u) {
            float w = __builtin_bit_cast(float, e[u].y);
#pragma unroll
            for (int j = 0; j < 4; ++j) acc[u & 3][j] += w * bf2f(h[u][j]);
        }
    }

    float sw = selfw[n];
    us4 sh = *(const us4*)(Hhi + (size_t)n * 128 + fo);
    f32x4 b4 = *(const f32x4*)(bias + l * 4);
    f32x4 sum = (acc[0] + acc[1]) + (acc[2] + acc[3]);
    f32x4 v;
    us4 ob;
#pragma unroll
    for (int j = 0; j < 4; ++j) {
        v[j] = fmaxf(sum[j] + sw * bf2f(sh[j]) + b4[j], 0.f);
        ob[j] = f2bf(v[j]);
    }
    if (outF) *(f32x4*)(outF + (size_t)n * 128 + fo) = v;
    *(us4*)(outHi + (size_t)n * 128 + fo) = ob;
}

// ---------------- launch ----------------
extern "C" void kernel_launch(void* const* d_in, const int* in_sizes, int n_in,
                              void* d_out, int out_size, void* d_ws, size_t ws_size,
                              hipStream_t stream)
{
    const float* x   = (const float*)d_in[0];
    const int*   ei  = (const int*)d_in[1];
    const float* W1  = (const float*)d_in[2];
    const float* b1  = (const float*)d_in[3];
    const float* W2  = (const float*)d_in[4];
    const float* b2  = (const float*)d_in[5];
    const float* Wp1 = (const float*)d_in[6];
    const float* bp1 = (const float*)d_in[7];
    const float* pa  = (const float*)d_in[8];
    const float* Wp2 = (const float*)d_in[9];
    const float* bp2 = (const float*)d_in[10];

    const int N = in_sizes[0] / 128;
    const int E = in_sizes[1] / 2;
    const int* src = ei;
    const int* dst = ei + E;

    float* outF = (float*)d_out;
    float* zbuf = outF;                        // output 0: z
    float* pbuf = outF + (size_t)N * 128;      // output 1: p

    char* w = (char*)d_ws;
    size_t off = 0;
    auto alloc = [&](size_t bytes) {
        void* p = w + off;
        off = (off + bytes + 255) & ~(size_t)255;
        return p;
    };
    unsigned short* S1 = (unsigned short*)alloc((size_t)N * 128 * sizeof(unsigned short));
    unsigned short* S2 = (unsigned short*)alloc((size_t)N * 128 * sizeof(unsigned short));
    float* dinv   = (float*)alloc((size_t)N * sizeof(float));
    float* selfw  = (float*)alloc((size_t)N * sizeof(float));
    int*   rowptr = (int*)alloc((size_t)(N + 1) * sizeof(int));
    int*   cnt    = (int*)alloc((size_t)N * sizeof(int));
    int*   cursor = (int*)alloc((size_t)N * sizeof(int));
    int*   bsum   = (int*)alloc(1024);
    int2*  epack  = (int2*)alloc(((size_t)E + 8 * (size_t)N) * sizeof(int2));
    unsigned short* wt = (unsigned short*)alloc((size_t)4 * 2 * 128 * 128 * sizeof(unsigned short));
    (void)ws_size; (void)n_in; (void)out_size;

    auto hiP = [&](int m) { return wt + (size_t)m * 32768; };
    auto loP = [&](int m) { return wt + (size_t)m * 32768 + 16384; };

    // CSR build (padded-to-8 edge lists) + weight prep
    hipMemsetAsync(cnt, 0, (size_t)N * sizeof(int), stream);
    const int nb = (N + 1023) >> 10;
    hipLaunchKernelGGL(prep_count, dim3(256 + (E + 255) / 256), dim3(256), 0, stream,
                       W1, W2, Wp1, Wp2, wt, dst, cnt, E);
    hipLaunchKernelGGL(scanA, dim3(nb), dim3(1024), 0, stream, cnt, rowptr, bsum, N);
    hipLaunchKernelGGL(scanB, dim3(1), dim3(128), 0, stream, bsum, nb, rowptr, N);
    hipLaunchKernelGGL(scanC, dim3((N + 255) / 256), dim3(256), 0, stream,
                       rowptr, bsum, cnt, cursor, dinv, selfw, N);
    hipLaunchKernelGGL(fill_csr, dim3((E + N + 255) / 256), dim3(256), 0, stream,
                       src, dst, cursor, dinv, rowptr, cnt, epack, N, E);

    const int gb = (N + 127) / 128;
    const int ab = (N + 7) / 8;
    // conv1: h1 = x@W1 (f32 A converted in-flight) -> S2 ; z1 = relu(agg+b1) -> S1
    hipLaunchKernelGGL(gemm128s, dim3(gb), dim3(256), 0, stream, (const void*)x, 1,
                       hiP(0), loP(0), S2, N);
    hipLaunchKernelGGL(aggregate, dim3(ab), dim3(256), 0, stream, S2, selfw, rowptr, epack,
                       b1, (float*)nullptr, S1, N);
    // conv2: h2 = z1@W2 -> S2 ; z = relu(agg+b2) -> zbuf(f32) + S1(bf16)
    hipLaunchKernelGGL(gemm128s, dim3(gb), dim3(256), 0, stream, (const void*)S1, 0,
                       hiP(1), loP(1), S2, N);
    hipLaunchKernelGGL(aggregate, dim3(ab), dim3(256), 0, stream, S2, selfw, rowptr, epack,
                       b2, zbuf, S1, N);
    // fused projection: p = prelu(z@Wp1+bp1)@Wp2+bp2 -> pbuf (T1 via S2)
    hipLaunchKernelGGL(proj2, dim3(gb), dim3(256), 0, stream, S1, hiP(2), hiP(3),
                       bp1, pa, bp2, S2, pbuf, N);
}